// Round 9
// baseline (167.182 us; speedup 1.0000x reference)
//
#include <hip/hip_runtime.h>
#include <hip/hip_bf16.h>
#include <cstddef>

#define NB  4
#define NC  256
#define NN  4096
#define DQK 32
#define MT  64       // query rows per flash block
#define JT  64       // key tile per iteration
#define NIT (NN / JT)
#define XS2 264      // proj LDS row stride in bf16 ([32 n][256 c] + 8 pad)

typedef __attribute__((ext_vector_type(8))) short short8;
typedef __attribute__((ext_vector_type(4))) float f32x4;

#define MFMA16(a, b, c) __builtin_amdgcn_mfma_f32_16x16x32_bf16((a), (b), (c), 0, 0, 0)

__device__ inline unsigned pk2bf(float a, float b) {
  __hip_bfloat162 h = __float22bfloat162_rn(make_float2(a, b));
  unsigned u;
  __builtin_memcpy(&u, &h, 4);
  return u;
}

// async global->LDS, 16B per lane; LDS dest = uniform base + lane*16 (linear),
// global src is per-lane (pre-swizzled to realize the XOR'd LDS layout).
__device__ inline void gl16(const void* g, void* s) {
  __builtin_amdgcn_global_load_lds(
      (const __attribute__((address_space(1))) void*)g,
      (__attribute__((address_space(3))) void*)s, 16, 0, 0);
}

// ---- W convert: [Wq(32);Wk(32);Wv(256)] f32 -> W16[320][256] bf16 ----
__global__ __launch_bounds__(256) void wcvt_kernel(
    const float* __restrict__ Wq, const float* __restrict__ Wk,
    const float* __restrict__ Wv, __hip_bfloat16* __restrict__ W16) {
  const int id4 = (blockIdx.x * 256 + threadIdx.x) * 4;   // 80 blocks -> 81920
  const int row = id4 >> 8, col = id4 & 255;
  const float* src = (row < 32) ? Wq + row * 256
                   : (row < 64) ? Wk + (row - 32) * 256
                                : Wv + (row - 64) * 256;
  float4 vv = *(const float4*)(src + col);
  *(uint2*)(W16 + id4) = make_uint2(pk2bf(vv.x, vv.y), pk2bf(vv.z, vv.w));
}

// ---- fused proj: stage x-slice to LDS once, ROLLED k-loop (unroll 1) with
// ---- one-step W-fragment prefetch. The full unroll hoisted 40 global b128
// ---- loads -> ~160 live VGPR -> scratch spills (the hidden ~75 us).
__global__ __launch_bounds__(256, 4) void proj_kernel(
    const float* __restrict__ x, const __hip_bfloat16* __restrict__ W16,
    const float* __restrict__ bq, const float* __restrict__ bk,
    const float* __restrict__ bv, __hip_bfloat16* __restrict__ q,
    __hip_bfloat16* __restrict__ kT, __hip_bfloat16* __restrict__ v) {
  __shared__ __hip_bfloat16 Xs[32 * XS2];   // 16896 B
  const int t = threadIdx.x;
  const int b = blockIdx.y, n0 = blockIdx.x * 32;
  const int w = __builtin_amdgcn_readfirstlane(t >> 6);   // wave: o rows [w*80, w*80+80)
  const int ln = t & 15, quad = (t & 63) >> 4;
  const int sn = t & 31, scg = t >> 5;   // staging: n lane, c-group (8 groups of 8)

  const float* xsrc = x + (size_t)b * NC * NN + n0 + sn;
#pragma unroll
  for (int g = 0; g < 4; ++g) {
    float xr[8];
#pragma unroll
    for (int i = 0; i < 8; ++i)
      xr[i] = xsrc[(size_t)(g * 64 + scg * 8 + i) * NN];
    uint4 pw;
    pw.x = pk2bf(xr[0], xr[1]);
    pw.y = pk2bf(xr[2], xr[3]);
    pw.z = pk2bf(xr[4], xr[5]);
    pw.w = pk2bf(xr[6], xr[7]);
    *(uint4*)&Xs[sn * XS2 + g * 64 + scg * 8] = pw;
  }
  __syncthreads();

  f32x4 zero4 = {0.f, 0.f, 0.f, 0.f};
  f32x4 acc[5][2];
#pragma unroll
  for (int i = 0; i < 5; ++i)
#pragma unroll
    for (int j = 0; j < 2; ++j) acc[i][j] = zero4;

  // W row base for this lane; afc = current k-step fragments (5), afn = next
  const __hip_bfloat16* wbase = W16 + (size_t)(w * 80 + ln) * NC + quad * 8;
  short8 afc[5], afn[5];
#pragma unroll
  for (int ot = 0; ot < 5; ++ot)
    afc[ot] = *(const short8*)(wbase + (size_t)ot * 16 * NC);

#pragma unroll 1
  for (int k0 = 0; k0 < NC; k0 += 32) {
    const int kn = k0 + 32;
    if (kn < NC) {
#pragma unroll
      for (int ot = 0; ot < 5; ++ot)
        afn[ot] = *(const short8*)(wbase + (size_t)ot * 16 * NC + kn);
    }
    short8 bfr[2];
#pragma unroll
    for (int nt = 0; nt < 2; ++nt)
      bfr[nt] = *(const short8*)&Xs[(nt * 16 + ln) * XS2 + k0 + quad * 8];
#pragma unroll
    for (int ot = 0; ot < 5; ++ot)
#pragma unroll
      for (int nt = 0; nt < 2; ++nt)
        acc[ot][nt] = MFMA16(afc[ot], bfr[nt], acc[ot][nt]);
#pragma unroll
    for (int ot = 0; ot < 5; ++ot) afc[ot] = afn[ot];
  }

  // epilogue: rows [0,32)->q[b][n][o], [32,64)->kT, [64,320)->v
#pragma unroll
  for (int ot = 0; ot < 5; ++ot) {
    const int gbase = w * 80 + ot * 16;    // wave-uniform
    if (gbase < 32) {
#pragma unroll
      for (int nt = 0; nt < 2; ++nt)
#pragma unroll
        for (int r = 0; r < 4; ++r) {
          const int row = gbase + quad * 4 + r;
          q[((size_t)b * NN + n0 + nt * 16 + ln) * DQK + row] =
              __hip_bfloat16(acc[ot][nt][r] + bq[row]);
        }
    } else if (gbase < 64) {
#pragma unroll
      for (int nt = 0; nt < 2; ++nt)
#pragma unroll
        for (int r = 0; r < 4; ++r) {
          const int row = gbase - 32 + quad * 4 + r;
          kT[((size_t)b * NN + n0 + nt * 16 + ln) * DQK + row] =
              __hip_bfloat16(acc[ot][nt][r] + bk[row]);
        }
    } else {
#pragma unroll
      for (int nt = 0; nt < 2; ++nt)
#pragma unroll
        for (int r = 0; r < 4; ++r) {
          const int c = gbase - 64 + quad * 4 + r;
          v[((size_t)b * NC + c) * NN + n0 + nt * 16 + ln] =
              __hip_bfloat16(acc[ot][nt][r] + bv[c]);
        }
    }
  }
}

// ---- wave-specialized flash with LDS-staged K and V via global_load_lds.
// ---- (unchanged from round 8 — frozen for attribution)
__global__ __launch_bounds__(512, 2) void flash_kernel(
    const __hip_bfloat16* __restrict__ q, const __hip_bfloat16* __restrict__ kt,
    const __hip_bfloat16* __restrict__ v, const float* __restrict__ x,
    const float* __restrict__ gamma, float* __restrict__ out) {
  __shared__ __align__(16) __hip_bfloat16 Ks[2][JT * DQK];    // 8 KB
  __shared__ __align__(16) __hip_bfloat16 Vs[2][NC * JT];     // 64 KB
  __shared__ __align__(16) __hip_bfloat16 Ps[2][MT * JT];     // 16 KB
  __shared__ float lrow[MT];

  const int t  = threadIdx.x;
  const int bi = blockIdx.x;
  // XCD swizzle: XCD pair {2b,2b+1} serves batch b -> K/V slices stay L2-local
  const int b  = (bi & 7) >> 1;
  const int m0 = (((bi & 1) * 32) + (bi >> 3)) * MT;

  const int w    = __builtin_amdgcn_readfirstlane(t >> 6);   // 0..7
  const int l    = t & 63;
  const int ln   = t & 15;
  const int quad = (t & 63) >> 4;

  const __hip_bfloat16* kb_base = kt + (size_t)b * NN * DQK;
  const __hip_bfloat16* v_base  = v + (size_t)b * NC * NN;

  size_t voff[4];
#pragma unroll
  for (int k = 0; k < 4; ++k) {
    const int g = w * 4 + k;
    const int c = g * 8 + (l >> 3);
    voff[k] = (size_t)c * NN + (((l & 7) ^ ((l >> 3) & 7)) * 8);
  }
  const size_t koff = (size_t)(w * 16 + (l >> 2)) * DQK +
                      (((l & 3) ^ ((l >> 2) & 3)) * 8);

  if (w < 4) gl16(kb_base + koff, &Ks[0][w * 512]);
  __syncthreads();

  if (w < 4) {
    const short8 qa =
        *(const short8*)(q + ((size_t)b * NN + m0 + w * 16 + ln) * DQK + quad * 8);
    float lreg = 0.f;
    const f32x4 zero4 = {0.f, 0.f, 0.f, 0.f};
    const int m = w * 16 + ln;

    for (int it = 0; it < NIT; ++it) {
#pragma unroll
      for (int k = 0; k < 4; ++k)
        gl16(v_base + voff[k] + (size_t)it * JT, &Vs[it & 1][(w * 4 + k) * 512]);
      if (it + 1 < NIT)
        gl16(kb_base + koff + (size_t)(it + 1) * JT * DQK, &Ks[(it + 1) & 1][w * 512]);

      short8 kb[4];
#pragma unroll
      for (int jt = 0; jt < 4; ++jt)
        kb[jt] = *(const short8*)&Ks[it & 1][(jt * 16 + ln) * DQK +
                                            ((quad ^ (ln & 3)) * 8)];
      f32x4 st[4];
      __builtin_amdgcn_s_setprio(1);
#pragma unroll
      for (int jt = 0; jt < 4; ++jt) st[jt] = MFMA16(kb[jt], qa, zero4);
      __builtin_amdgcn_s_setprio(0);

      char* pbase = (char*)&Ps[it & 1][0] + m * (JT * 2);
#pragma unroll
      for (int jt = 0; jt < 4; ++jt) {
        const float e0 = __expf(st[jt][0]), e1 = __expf(st[jt][1]);
        const float e2 = __expf(st[jt][2]), e3 = __expf(st[jt][3]);
        lreg += (e0 + e1) + (e2 + e3);
        *(uint2*)(pbase + ((jt * 32 + quad * 8) ^ ((m & 7) << 4))) =
            make_uint2(pk2bf(e0, e1), pk2bf(e2, e3));
      }
      __syncthreads();
    }
    lreg += __shfl_xor(lreg, 16);
    lreg += __shfl_xor(lreg, 32);
    if (quad == 0) lrow[w * 16 + ln] = lreg;
    __syncthreads();
  } else {
    const int c0 = (w - 4) * 64;
    const f32x4 zero4 = {0.f, 0.f, 0.f, 0.f};
    f32x4 acc[4][4];
#pragma unroll
    for (int ct = 0; ct < 4; ++ct)
#pragma unroll
      for (int mt = 0; mt < 4; ++mt) acc[ct][mt] = zero4;

    for (int it = 0; it < NIT; ++it) {
#pragma unroll
      for (int k = 0; k < 4; ++k)
        gl16(v_base + voff[k] + (size_t)it * JT, &Vs[it & 1][(w * 4 + k) * 512]);

      if (it > 0) {
        const int pbuf = (it - 1) & 1;
        const char* pbase = (const char*)&Ps[pbuf][0];
        short8 va[4][2];
#pragma unroll
        for (int ct = 0; ct < 4; ++ct)
#pragma unroll
          for (int ks = 0; ks < 2; ++ks)
            va[ct][ks] = *(const short8*)&Vs[pbuf][
                (c0 + ct * 16 + ln) * JT + (((ks * 4 + quad) ^ (ln & 7)) * 8)];
#pragma unroll
        for (int ks = 0; ks < 2; ++ks) {
          short8 pb[4];
#pragma unroll
          for (int mt = 0; mt < 4; ++mt)
            pb[mt] = *(const short8*)(pbase + (mt * 16 + ln) * (JT * 2) +
                                      ((ks * 64 + quad * 16) ^ ((ln & 7) << 4)));
          __builtin_amdgcn_s_setprio(1);
#pragma unroll
          for (int ct = 0; ct < 4; ++ct)
#pragma unroll
            for (int mt = 0; mt < 4; ++mt)
              acc[ct][mt] = MFMA16(va[ct][ks], pb[mt], acc[ct][mt]);
          __builtin_amdgcn_s_setprio(0);
        }
      }
      __syncthreads();
    }

    {
      const int pbuf = (NIT - 1) & 1;
      const char* pbase = (const char*)&Ps[pbuf][0];
      short8 va[4][2];
#pragma unroll
      for (int ct = 0; ct < 4; ++ct)
#pragma unroll
        for (int ks = 0; ks < 2; ++ks)
          va[ct][ks] = *(const short8*)&Vs[pbuf][
              (c0 + ct * 16 + ln) * JT + (((ks * 4 + quad) ^ (ln & 7)) * 8)];
#pragma unroll
      for (int ks = 0; ks < 2; ++ks) {
        short8 pb[4];
#pragma unroll
        for (int mt = 0; mt < 4; ++mt)
          pb[mt] = *(const short8*)(pbase + (mt * 16 + ln) * (JT * 2) +
                                    ((ks * 64 + quad * 16) ^ ((ln & 7) << 4)));
        __builtin_amdgcn_s_setprio(1);
#pragma unroll
        for (int ct = 0; ct < 4; ++ct)
#pragma unroll
          for (int mt = 0; mt < 4; ++mt)
            acc[ct][mt] = MFMA16(va[ct][ks], pb[mt], acc[ct][mt]);
        __builtin_amdgcn_s_setprio(0);
      }
    }
    __syncthreads();

    const float g0 = gamma[0];
    float li[4];
#pragma unroll
    for (int mt = 0; mt < 4; ++mt) li[mt] = 1.f / lrow[mt * 16 + ln];
#pragma unroll
    for (int ct = 0; ct < 4; ++ct)
#pragma unroll
      for (int r = 0; r < 4; ++r) {
        const int c = c0 + ct * 16 + quad * 4 + r;
        const float* xr = x + ((size_t)b * NC + c) * NN + m0;
        float* orow = out + ((size_t)b * NC + c) * NN + m0;
#pragma unroll
        for (int mt = 0; mt < 4; ++mt) {
          const int m = mt * 16 + ln;
          orow[m] = g0 * (acc[ct][mt][r] * li[mt]) + xr[m];
        }
      }
  }
}

extern "C" void kernel_launch(void* const* d_in, const int* in_sizes, int n_in,
                              void* d_out, int out_size, void* d_ws, size_t ws_size,
                              hipStream_t stream) {
  const float* x     = (const float*)d_in[0];
  const float* Wq    = (const float*)d_in[1];
  const float* bq    = (const float*)d_in[2];
  const float* Wk    = (const float*)d_in[3];
  const float* bk    = (const float*)d_in[4];
  const float* Wv    = (const float*)d_in[5];
  const float* bv    = (const float*)d_in[6];
  const float* gamma = (const float*)d_in[7];
  float* out = (float*)d_out;

  char* wsp = (char*)d_ws;
  __hip_bfloat16* W16 = (__hip_bfloat16*)wsp;  wsp += (size_t)320 * NC * 2;
  __hip_bfloat16* q   = (__hip_bfloat16*)wsp;  wsp += (size_t)NB * NN * DQK * 2;
  __hip_bfloat16* kT  = (__hip_bfloat16*)wsp;  wsp += (size_t)NB * NN * DQK * 2;
  __hip_bfloat16* v   = (__hip_bfloat16*)wsp;  // + 8.4 MB => ~10.6 MB total

  wcvt_kernel<<<dim3(80), dim3(256), 0, stream>>>(Wq, Wk, Wv, W16);
  proj_kernel<<<dim3(NN / 32, NB), dim3(256), 0, stream>>>(x, W16, bq, bk, bv, q, kT, v);
  flash_kernel<<<dim3(NB * NN / MT), dim3(512), 0, stream>>>(q, kT, v, x, gamma, out);
}